// Round 1
// baseline (805.595 us; speedup 1.0000x reference)
//
#include <hip/hip_runtime.h>
#include <math.h>

#define N0 16
#define N1 200
#define N2 200
#define NPIX (N1 * N2)            // 40000
#define NVOX (N0 * NPIX)          // 640000
#define NUM_RAD 223
#define NUM_PHI 190
#define NUM_T 351
#define NSINO (N0 * NUM_PHI * NUM_RAD)  // 677920
#define ORG1F (-199.0f)
#define ORG2F (-199.0f)

// ---------------- constants: replicate numpy linspace / cos / gaussian ----------------
__global__ void init_consts(float* __restrict__ cosb, float* __restrict__ sinb,
                            float* __restrict__ rvb, float* __restrict__ gwb) {
    int t = threadIdx.x;
    const double PI = 3.14159265358979311599796346854418516159;
    if (t < NUM_PHI) {
        double step = PI / 190.0;             // np.linspace(0, pi, 190, endpoint=False)
        float phif = (float)((double)t * step);
        cosb[t] = (float)cos((double)phif);   // np.cos on float32 input
        sinb[t] = (float)sin((double)phif);
    }
    if (t < NUM_RAD) {
        double step = 400.0 / 222.0;          // np.linspace(-200, 200, 223)
        float rv = (float)(-200.0 + (double)t * step);
        if (t == NUM_RAD - 1) rv = 200.0f;    // linspace endpoint fixup
        rvb[t] = rv;
    }
    if (t == 0) {
        double sig = 4.5 / (2.35 * 2.0);
        double g[9], ssum = 0.0;
        for (int k = 0; k < 9; ++k) { double d = (double)(k - 4) / sig; g[k] = exp(-0.5 * d * d); ssum += g[k]; }
        for (int k = 0; k < 9; ++k) gwb[k] = (float)(g[k] / ssum);
    }
}

// ---------------- separable gaussian, forward (symmetric pad) ----------------
__global__ void smooth_fwd(const float* __restrict__ in, float* __restrict__ out,
                           const float* __restrict__ gwb, int n, int stride) {
    int e = blockIdx.x * 256 + threadIdx.x;
    if (e >= NVOX) return;
    int a = (e / stride) % n;
    int base = e - a * stride;
    float sum = 0.f;
#pragma unroll
    for (int k = 0; k < 9; ++k) {
        int q = a + k - 4;
        q = (q < 0) ? (-1 - q) : ((q >= n) ? (2 * n - 1 - q) : q);
        sum = __fadd_rn(sum, __fmul_rn(gwb[k], in[base + q * stride]));
    }
    out[e] = sum;
}

// ---------------- separable gaussian, adjoint (pad-transpose fold) ----------------
__device__ __forceinline__ float adj_u(const float* __restrict__ in, const float* __restrict__ gwb,
                                       int base, int stride, int n, int j) {
    float r = 0.f;
#pragma unroll
    for (int k = 0; k < 9; ++k) {
        int i = j - k;
        if (i >= 0 && i < n) r = __fadd_rn(r, __fmul_rn(gwb[k], in[base + i * stride]));
    }
    return r;
}

__global__ void smooth_adj(const float* __restrict__ in, float* __restrict__ out,
                           const float* __restrict__ gwb, int n, int stride) {
    int e = blockIdx.x * 256 + threadIdx.x;
    if (e >= NVOX) return;
    int a = (e / stride) % n;
    int base = e - a * stride;
    float v = adj_u(in, gwb, base, stride, n, a + 4);
    if (a < 4)      v = __fadd_rn(v, adj_u(in, gwb, base, stride, n, 3 - a));
    if (a >= n - 4) v = __fadd_rn(v, adj_u(in, gwb, base, stride, n, 2 * n + 3 - a));
    out[e] = v;
}

// final axis-0 adjoint pass fused with  out = x * v / sens
__global__ void smooth_adj0_final(const float* __restrict__ in, const float* __restrict__ x,
                                  const float* __restrict__ sens, const float* __restrict__ gwb,
                                  float* __restrict__ out) {
    int e = blockIdx.x * 256 + threadIdx.x;
    if (e >= NVOX) return;
    int a = e / NPIX;
    int base = e - a * NPIX;
    float v = adj_u(in, gwb, base, NPIX, N0, a + 4);
    if (a < 4)  v = __fadd_rn(v, adj_u(in, gwb, base, NPIX, N0, 3 - a));
    if (a >= 12) v = __fadd_rn(v, adj_u(in, gwb, base, NPIX, N0, 35 - a));
    out[e] = __fdiv_rn(__fmul_rn(x[e], v), sens[e]);
}

// ---------------- forward projection + ratio, fused ----------------
// block: (phi, i0), thread = radial bin r. Writes z = mult*data/(mult*proj+contam)
// transposed to zt[phi][r][i0] for the backprojector.
__global__ void project_ratio(const float* __restrict__ simg, const float* __restrict__ data,
                              const float* __restrict__ contam, const float* __restrict__ mult,
                              const float* __restrict__ cosb, const float* __restrict__ sinb,
                              const float* __restrict__ rvb, float* __restrict__ zt) {
    int phi = blockIdx.x;
    int i0 = blockIdx.y;
    int r = threadIdx.x;
    if (r >= NUM_RAD) return;
    float c = cosb[phi], sp = sinb[phi];
    float rv = rvb[r];
    float A = __fmul_rn(rv, -sp);   // RV * (-s)
    float B = __fmul_rn(rv, c);     // RV * c
    const float* sl = simg + i0 * NPIX;
    float sum = 0.f;
    for (int k = 0; k < NUM_T; ++k) {
        float tv = (float)(2 * k - 350);
        float ix = __fmul_rn(__fsub_rn(__fadd_rn(A, __fmul_rn(tv, c)), ORG1F), 0.5f);
        float iy = __fmul_rn(__fsub_rn(__fadd_rn(B, __fmul_rn(tv, sp)), ORG2F), 0.5f);
        if (!(ix >= 0.f && ix <= 199.f && iy >= 0.f && iy <= 199.f)) continue;
        float fx = floorf(ix), fy = floorf(iy);
        int ii = (int)fx, jj = (int)fy;
        float fi = ix - fx, fj = iy - fy;
        int ii1 = ii + 1 > 199 ? 199 : ii + 1;
        int jj1 = jj + 1 > 199 ? 199 : jj + 1;
        float v00 = sl[ii * N2 + jj], v10 = sl[ii1 * N2 + jj];
        float v01 = sl[ii * N2 + jj1], v11 = sl[ii1 * N2 + jj1];
        float v = (1.f - fi) * (1.f - fj) * v00 + fi * (1.f - fj) * v10
                + (1.f - fi) * fj * v01 + fi * fj * v11;
        sum += v;
    }
    float proj = __fmul_rn(sum, 2.0f);  // * STEP
    int idx = (i0 * NUM_PHI + phi) * NUM_RAD + r;
    float ex = __fadd_rn(__fmul_rn(mult[idx], proj), contam[idx]);
    float zval = __fmul_rn(mult[idx], __fdiv_rn(data[idx], ex));
    zt[(phi * NUM_RAD + r) * N0 + i0] = zval;
}

// ---------------- adjoint projection, gather form ----------------
// thread = (pixel, phi-chunk of 19). Accumulates all 16 slices, atomicAdd into bp[i0][pix].
__global__ void backproject(const float* __restrict__ zt, const float* __restrict__ cosb,
                            const float* __restrict__ sinb, const float* __restrict__ rvb,
                            float* __restrict__ bp) {
    int g = blockIdx.x * 256 + threadIdx.x;
    if (g >= NPIX * 10) return;
    int pc = g / NPIX;
    int pix = g - pc * NPIX;
    int i1 = pix / N2;
    int i2 = pix - i1 * N2;
    float X1 = 2.f * (float)i1 - 199.f;   // ORG1 + i1*VOX (exact)
    float X2 = 2.f * (float)i2 - 199.f;
    float acc[N0];
#pragma unroll
    for (int i0 = 0; i0 < N0; ++i0) acc[i0] = 0.f;

    int p_end = pc * 19 + 19;
    for (int p = pc * 19; p < p_end; ++p) {
        float c = cosb[p], sp = sinb[p];
        float tp = c * X1 + sp * X2;      // candidate location only (precision uncritical)
        float rp = c * X2 - sp * X1;
        int j0 = (int)floorf((rp + 200.f) * 0.555f);   // 222/400
        int k0 = (int)floorf((tp + 350.f) * 0.5f);
        for (int dj = -1; dj <= 2; ++dj) {
            int j = j0 + dj;
            if (j < 0 || j > NUM_RAD - 1) continue;
            float rv = rvb[j];
            float A = __fmul_rn(rv, -sp);
            float B = __fmul_rn(rv, c);
            float w = 0.f;
            for (int dk = -1; dk <= 2; ++dk) {
                int k = k0 + dk;
                if (k < 0 || k > NUM_T - 1) continue;
                float tv = (float)(2 * k - 350);
                // EXACT same op sequence as forward -> identical ix/iy/validity
                float ix = __fmul_rn(__fsub_rn(__fadd_rn(A, __fmul_rn(tv, c)), ORG1F), 0.5f);
                float iy = __fmul_rn(__fsub_rn(__fadd_rn(B, __fmul_rn(tv, sp)), ORG2F), 0.5f);
                if (!(ix >= 0.f && ix <= 199.f && iy >= 0.f && iy <= 199.f)) continue;
                float fx = floorf(ix), fy = floorf(iy);
                int ii = (int)fx, jj = (int)fy;
                float fi = ix - fx, fj = iy - fy;
                float wx = (ii == i1) ? (1.f - fi) : ((ii + 1 == i1) ? fi : 0.f);
                if (wx == 0.f) continue;
                float wy = (jj == i2) ? (1.f - fj) : ((jj + 1 == i2) ? fj : 0.f);
                w += wx * wy;
            }
            if (w != 0.f) {
                const float* zp = zt + (p * NUM_RAD + j) * N0;
#pragma unroll
                for (int i0 = 0; i0 < N0; ++i0) acc[i0] += w * zp[i0];
            }
        }
    }
#pragma unroll
    for (int i0 = 0; i0 < N0; ++i0)
        atomicAdd(&bp[i0 * NPIX + pix], acc[i0] * 2.0f);  // * STEP
}

extern "C" void kernel_launch(void* const* d_in, const int* in_sizes, int n_in,
                              void* d_out, int out_size, void* d_ws, size_t ws_size,
                              hipStream_t stream) {
    const float* x      = (const float*)d_in[0];
    const float* data   = (const float*)d_in[1];
    const float* contam = (const float*)d_in[2];
    const float* mult   = (const float*)d_in[3];
    const float* sens   = (const float*)d_in[4];
    float* out = (float*)d_out;

    float* W    = (float*)d_ws;
    float* s    = W;                       // 640000
    float* tmp  = W + NVOX;                // 640000
    float* bp   = W + 2 * NVOX;            // 640000
    float* zt   = W + 3 * NVOX;            // 677920
    float* cosb = W + 3 * NVOX + NSINO;
    float* sinb = cosb + NUM_PHI;
    float* rvb  = sinb + NUM_PHI;
    float* gwb  = rvb + NUM_RAD;

    hipLaunchKernelGGL(init_consts, dim3(1), dim3(256), 0, stream, cosb, sinb, rvb, gwb);

    // gauss3 forward: x -> s (axis0), s -> tmp (axis1), tmp -> s (axis2)
    int nb = (NVOX + 255) / 256;
    hipLaunchKernelGGL(smooth_fwd, dim3(nb), dim3(256), 0, stream, x,   s,   gwb, N0, NPIX);
    hipLaunchKernelGGL(smooth_fwd, dim3(nb), dim3(256), 0, stream, s,   tmp, gwb, N1, N2);
    hipLaunchKernelGGL(smooth_fwd, dim3(nb), dim3(256), 0, stream, tmp, s,   gwb, N2, 1);

    // forward project + ratio (writes zt)
    hipLaunchKernelGGL(project_ratio, dim3(NUM_PHI, N0), dim3(256), 0, stream,
                       s, data, contam, mult, cosb, sinb, rvb, zt);

    // backproject (gather) into bp
    hipMemsetAsync(bp, 0, NVOX * sizeof(float), stream);
    int nb2 = (NPIX * 10 + 255) / 256;
    hipLaunchKernelGGL(backproject, dim3(nb2), dim3(256), 0, stream, zt, cosb, sinb, rvb, bp);

    // gauss3 adjoint: bp -> tmp (axis2^T), tmp -> bp (axis1^T), bp -> out (axis0^T fused final)
    hipLaunchKernelGGL(smooth_adj, dim3(nb), dim3(256), 0, stream, bp,  tmp, gwb, N2, 1);
    hipLaunchKernelGGL(smooth_adj, dim3(nb), dim3(256), 0, stream, tmp, bp,  gwb, N1, N2);
    hipLaunchKernelGGL(smooth_adj0_final, dim3(nb), dim3(256), 0, stream, bp, x, sens, gwb, out);
}

// Round 2
// 742.700 us; speedup vs baseline: 1.0847x; 1.0847x over previous
//
#include <hip/hip_runtime.h>
#include <math.h>

#define N0 16
#define N1 200
#define N2 200
#define NPIX (N1 * N2)            // 40000
#define NVOX (N0 * NPIX)          // 640000
#define NUM_RAD 223
#define NUM_PHI 190
#define NUM_T 351
#define NSINO (N0 * NUM_PHI * NUM_RAD)  // 677920
#define ORG1F (-199.0f)
#define ORG2F (-199.0f)

// ---------------- constants: replicate numpy linspace / cos / gaussian ----------------
__global__ void init_consts(float* __restrict__ cosb, float* __restrict__ sinb,
                            float* __restrict__ rvb, float* __restrict__ gwb) {
    int t = threadIdx.x;
    const double PI = 3.14159265358979311599796346854418516159;
    if (t < NUM_PHI) {
        double step = PI / 190.0;             // np.linspace(0, pi, 190, endpoint=False)
        float phif = (float)((double)t * step);
        cosb[t] = (float)cos((double)phif);   // np.cos on float32 input
        sinb[t] = (float)sin((double)phif);
    }
    if (t < NUM_RAD) {
        double step = 400.0 / 222.0;          // np.linspace(-200, 200, 223)
        float rv = (float)(-200.0 + (double)t * step);
        if (t == NUM_RAD - 1) rv = 200.0f;    // linspace endpoint fixup
        rvb[t] = rv;
    }
    if (t == 0) {
        double sig = 4.5 / (2.35 * 2.0);
        double g[9], ssum = 0.0;
        for (int k = 0; k < 9; ++k) { double d = (double)(k - 4) / sig; g[k] = exp(-0.5 * d * d); ssum += g[k]; }
        for (int k = 0; k < 9; ++k) gwb[k] = (float)(g[k] / ssum);
    }
}

// ---------------- separable gaussian, forward (symmetric pad) ----------------
__global__ void smooth_fwd(const float* __restrict__ in, float* __restrict__ out,
                           const float* __restrict__ gwb, int n, int stride) {
    int e = blockIdx.x * 256 + threadIdx.x;
    if (e >= NVOX) return;
    int a = (e / stride) % n;
    int base = e - a * stride;
    float sum = 0.f;
#pragma unroll
    for (int k = 0; k < 9; ++k) {
        int q = a + k - 4;
        q = (q < 0) ? (-1 - q) : ((q >= n) ? (2 * n - 1 - q) : q);
        sum = __fadd_rn(sum, __fmul_rn(gwb[k], in[base + q * stride]));
    }
    out[e] = sum;
}

// ---------------- separable gaussian, adjoint (pad-transpose fold) ----------------
__device__ __forceinline__ float adj_u(const float* __restrict__ in, const float* __restrict__ gwb,
                                       int base, int stride, int n, int j) {
    float r = 0.f;
#pragma unroll
    for (int k = 0; k < 9; ++k) {
        int i = j - k;
        if (i >= 0 && i < n) r = __fadd_rn(r, __fmul_rn(gwb[k], in[base + i * stride]));
    }
    return r;
}

__global__ void smooth_adj(const float* __restrict__ in, float* __restrict__ out,
                           const float* __restrict__ gwb, int n, int stride) {
    int e = blockIdx.x * 256 + threadIdx.x;
    if (e >= NVOX) return;
    int a = (e / stride) % n;
    int base = e - a * stride;
    float v = adj_u(in, gwb, base, stride, n, a + 4);
    if (a < 4)      v = __fadd_rn(v, adj_u(in, gwb, base, stride, n, 3 - a));
    if (a >= n - 4) v = __fadd_rn(v, adj_u(in, gwb, base, stride, n, 2 * n + 3 - a));
    out[e] = v;
}

// final axis-0 adjoint pass fused with  out = x * v / sens
__global__ void smooth_adj0_final(const float* __restrict__ in, const float* __restrict__ x,
                                  const float* __restrict__ sens, const float* __restrict__ gwb,
                                  float* __restrict__ out) {
    int e = blockIdx.x * 256 + threadIdx.x;
    if (e >= NVOX) return;
    int a = e / NPIX;
    int base = e - a * NPIX;
    float v = adj_u(in, gwb, base, NPIX, N0, a + 4);
    if (a < 4)  v = __fadd_rn(v, adj_u(in, gwb, base, NPIX, N0, 3 - a));
    if (a >= 12) v = __fadd_rn(v, adj_u(in, gwb, base, NPIX, N0, 35 - a));
    out[e] = __fdiv_rn(__fmul_rn(x[e], v), sens[e]);
}

// ---------------- forward projection + ratio, fused ----------------
// block: (phi, i0-pair), thread = radial bin r; each thread traces one ray
// through TWO slices (shared address math). Valid-t-range computed per ray
// (conservative, per-sample predication keeps numerics exact).
__global__ void project_ratio(const float* __restrict__ simg, const float* __restrict__ data,
                              const float* __restrict__ contam, const float* __restrict__ mult,
                              const float* __restrict__ cosb, const float* __restrict__ sinb,
                              const float* __restrict__ rvb, float* __restrict__ zt) {
    int phi = blockIdx.x;
    int i0 = blockIdx.y * 2;
    int r = threadIdx.x;
    if (r >= NUM_RAD) return;
    float c = cosb[phi], sp = sinb[phi];
    float rv = rvb[r];
    float A = __fmul_rn(rv, -sp);   // RV * (-s)
    float B = __fmul_rn(rv, c);     // RV * c

    // conservative valid-t window: A + tv*c in [-199,199] and B + tv*sp in [-199,199]
    float tlo = -350.f, thi = 350.f;
    bool empty = false;
    {
        if (fabsf(c) > 1e-6f) {
            float a0 = (-199.f - A) / c, b0 = (199.f - A) / c;
            tlo = fmaxf(tlo, fminf(a0, b0)); thi = fminf(thi, fmaxf(a0, b0));
        } else if (fabsf(A) > 199.5f) empty = true;
        if (fabsf(sp) > 1e-6f) {
            float a0 = (-199.f - B) / sp, b0 = (199.f - B) / sp;
            tlo = fmaxf(tlo, fminf(a0, b0)); thi = fminf(thi, fmaxf(a0, b0));
        } else if (fabsf(B) > 199.5f) empty = true;
    }
    int klo = max(0, (int)floorf((tlo + 350.f) * 0.5f) - 1);
    int khi = min(NUM_T - 1, (int)ceilf((thi + 350.f) * 0.5f) + 1);

    const float* sl0 = simg + i0 * NPIX;
    const float* sl1 = sl0 + NPIX;
    float sum0 = 0.f, sum1 = 0.f;
    if (!empty && klo <= khi) {
#pragma unroll 4
        for (int k = klo; k <= khi; ++k) {
            float tv = (float)(2 * k - 350);
            float ix = __fmul_rn(__fsub_rn(__fadd_rn(A, __fmul_rn(tv, c)), ORG1F), 0.5f);
            float iy = __fmul_rn(__fsub_rn(__fadd_rn(B, __fmul_rn(tv, sp)), ORG2F), 0.5f);
            bool valid = (ix >= 0.f && ix <= 199.f && iy >= 0.f && iy <= 199.f);
            float fx = floorf(ix), fy = floorf(iy);
            int ii = (int)fx, jj = (int)fy;
            float fi = ix - fx, fj = iy - fy;
            // clamp for safe loads when invalid (weights match reference clip when valid)
            int ii0 = min(max(ii, 0), 199), jj0 = min(max(jj, 0), 199);
            int ii1 = min(ii0 + 1, 199),   jj1 = min(jj0 + 1, 199);
            float w00 = (1.f - fi) * (1.f - fj), w10 = fi * (1.f - fj);
            float w01 = (1.f - fi) * fj,         w11 = fi * fj;
            int o00 = ii0 * N2 + jj0, o10 = ii1 * N2 + jj0;
            int o01 = ii0 * N2 + jj1, o11 = ii1 * N2 + jj1;
            float v0 = w00 * sl0[o00] + w10 * sl0[o10] + w01 * sl0[o01] + w11 * sl0[o11];
            float v1 = w00 * sl1[o00] + w10 * sl1[o10] + w01 * sl1[o01] + w11 * sl1[o11];
            float m = valid ? 1.f : 0.f;
            sum0 = __fadd_rn(sum0, __fmul_rn(v0, m));
            sum1 = __fadd_rn(sum1, __fmul_rn(v1, m));
        }
    }
#pragma unroll
    for (int s = 0; s < 2; ++s) {
        float proj = __fmul_rn(s ? sum1 : sum0, 2.0f);  // * STEP
        int sl = i0 + s;
        int idx = (sl * NUM_PHI + phi) * NUM_RAD + r;
        float ex = __fadd_rn(__fmul_rn(mult[idx], proj), contam[idx]);
        float zval = __fmul_rn(mult[idx], __fdiv_rn(data[idx], ex));
        zt[(phi * NUM_RAD + r) * N0 + sl] = zval;
    }
}

// ---------------- adjoint projection, gather form ----------------
// thread = (pixel, phi-chunk of 19). Accumulates all 16 slices, atomicAdd into bp[i0][pix].
__global__ void backproject(const float* __restrict__ zt, const float* __restrict__ cosb,
                            const float* __restrict__ sinb, const float* __restrict__ rvb,
                            float* __restrict__ bp) {
    int g = blockIdx.x * 256 + threadIdx.x;
    if (g >= NPIX * 10) return;
    int pc = g / NPIX;
    int pix = g - pc * NPIX;
    int i1 = pix / N2;
    int i2 = pix - i1 * N2;
    float X1 = 2.f * (float)i1 - 199.f;   // ORG1 + i1*VOX (exact)
    float X2 = 2.f * (float)i2 - 199.f;
    float acc[N0];
#pragma unroll
    for (int i0 = 0; i0 < N0; ++i0) acc[i0] = 0.f;

    int p_end = pc * 19 + 19;
    for (int p = pc * 19; p < p_end; ++p) {
        float c = cosb[p], sp = sinb[p];
        float tp = c * X1 + sp * X2;      // candidate location only (precision uncritical)
        float rp = c * X2 - sp * X1;
        int j0 = (int)floorf((rp + 200.f) * 0.555f);   // 222/400
        int k0 = (int)floorf((tp + 350.f) * 0.5f);
        for (int dj = -1; dj <= 2; ++dj) {
            int j = j0 + dj;
            if (j < 0 || j > NUM_RAD - 1) continue;
            float rv = rvb[j];
            float A = __fmul_rn(rv, -sp);
            float B = __fmul_rn(rv, c);
            float w = 0.f;
            for (int dk = -1; dk <= 2; ++dk) {
                int k = k0 + dk;
                if (k < 0 || k > NUM_T - 1) continue;
                float tv = (float)(2 * k - 350);
                // EXACT same op sequence as forward -> identical ix/iy/validity
                float ix = __fmul_rn(__fsub_rn(__fadd_rn(A, __fmul_rn(tv, c)), ORG1F), 0.5f);
                float iy = __fmul_rn(__fsub_rn(__fadd_rn(B, __fmul_rn(tv, sp)), ORG2F), 0.5f);
                if (!(ix >= 0.f && ix <= 199.f && iy >= 0.f && iy <= 199.f)) continue;
                float fx = floorf(ix), fy = floorf(iy);
                int ii = (int)fx, jj = (int)fy;
                float fi = ix - fx, fj = iy - fy;
                float wx = (ii == i1) ? (1.f - fi) : ((ii + 1 == i1) ? fi : 0.f);
                if (wx == 0.f) continue;
                float wy = (jj == i2) ? (1.f - fj) : ((jj + 1 == i2) ? fj : 0.f);
                w += wx * wy;
            }
            if (w != 0.f) {
                const float* zp = zt + (p * NUM_RAD + j) * N0;
#pragma unroll
                for (int i0 = 0; i0 < N0; ++i0) acc[i0] += w * zp[i0];
            }
        }
    }
#pragma unroll
    for (int i0 = 0; i0 < N0; ++i0)
        atomicAdd(&bp[i0 * NPIX + pix], acc[i0] * 2.0f);  // * STEP
}

extern "C" void kernel_launch(void* const* d_in, const int* in_sizes, int n_in,
                              void* d_out, int out_size, void* d_ws, size_t ws_size,
                              hipStream_t stream) {
    const float* x      = (const float*)d_in[0];
    const float* data   = (const float*)d_in[1];
    const float* contam = (const float*)d_in[2];
    const float* mult   = (const float*)d_in[3];
    const float* sens   = (const float*)d_in[4];
    float* out = (float*)d_out;

    float* W    = (float*)d_ws;
    float* s    = W;                       // 640000
    float* tmp  = W + NVOX;                // 640000
    float* bp   = W + 2 * NVOX;            // 640000
    float* zt   = W + 3 * NVOX;            // 677920
    float* cosb = W + 3 * NVOX + NSINO;
    float* sinb = cosb + NUM_PHI;
    float* rvb  = sinb + NUM_PHI;
    float* gwb  = rvb + NUM_RAD;

    hipLaunchKernelGGL(init_consts, dim3(1), dim3(256), 0, stream, cosb, sinb, rvb, gwb);

    // gauss3 forward: x -> s (axis0), s -> tmp (axis1), tmp -> s (axis2)
    int nb = (NVOX + 255) / 256;
    hipLaunchKernelGGL(smooth_fwd, dim3(nb), dim3(256), 0, stream, x,   s,   gwb, N0, NPIX);
    hipLaunchKernelGGL(smooth_fwd, dim3(nb), dim3(256), 0, stream, s,   tmp, gwb, N1, N2);
    hipLaunchKernelGGL(smooth_fwd, dim3(nb), dim3(256), 0, stream, tmp, s,   gwb, N2, 1);

    // forward project + ratio (writes zt), 2 slices per thread
    hipLaunchKernelGGL(project_ratio, dim3(NUM_PHI, N0 / 2), dim3(256), 0, stream,
                       s, data, contam, mult, cosb, sinb, rvb, zt);

    // backproject (gather) into bp
    hipMemsetAsync(bp, 0, NVOX * sizeof(float), stream);
    int nb2 = (NPIX * 10 + 255) / 256;
    hipLaunchKernelGGL(backproject, dim3(nb2), dim3(256), 0, stream, zt, cosb, sinb, rvb, bp);

    // gauss3 adjoint: bp -> tmp (axis2^T), tmp -> bp (axis1^T), bp -> out (axis0^T fused final)
    hipLaunchKernelGGL(smooth_adj, dim3(nb), dim3(256), 0, stream, bp,  tmp, gwb, N2, 1);
    hipLaunchKernelGGL(smooth_adj, dim3(nb), dim3(256), 0, stream, tmp, bp,  gwb, N1, N2);
    hipLaunchKernelGGL(smooth_adj0_final, dim3(nb), dim3(256), 0, stream, bp, x, sens, gwb, out);
}

// Round 3
// 651.304 us; speedup vs baseline: 1.2369x; 1.1403x over previous
//
#include <hip/hip_runtime.h>
#include <math.h>

#define N0 16
#define N1 200
#define N2 200
#define NPIX (N1 * N2)            // 40000
#define NVOX (N0 * NPIX)          // 640000
#define NUM_RAD 223
#define NUM_PHI 190
#define NUM_T 351
#define NSINO (N0 * NUM_PHI * NUM_RAD)  // 677920
#define ORG1F (-199.0f)
#define ORG2F (-199.0f)

// ---------------- constants: replicate numpy linspace / cos / gaussian ----------------
__global__ void init_consts(float* __restrict__ cosb, float* __restrict__ sinb,
                            float* __restrict__ rvb, float* __restrict__ gwb) {
    int t = threadIdx.x;
    const double PI = 3.14159265358979311599796346854418516159;
    if (t < NUM_PHI) {
        double step = PI / 190.0;             // np.linspace(0, pi, 190, endpoint=False)
        float phif = (float)((double)t * step);
        cosb[t] = (float)cos((double)phif);   // np.cos on float32 input
        sinb[t] = (float)sin((double)phif);
    }
    if (t < NUM_RAD) {
        double step = 400.0 / 222.0;          // np.linspace(-200, 200, 223)
        float rv = (float)(-200.0 + (double)t * step);
        if (t == NUM_RAD - 1) rv = 200.0f;    // linspace endpoint fixup
        rvb[t] = rv;
    }
    if (t == 0) {
        double sig = 4.5 / (2.35 * 2.0);
        double g[9], ssum = 0.0;
        for (int k = 0; k < 9; ++k) { double d = (double)(k - 4) / sig; g[k] = exp(-0.5 * d * d); ssum += g[k]; }
        for (int k = 0; k < 9; ++k) gwb[k] = (float)(g[k] / ssum);
    }
}

// ---------------- separable gaussian, forward (symmetric pad) ----------------
__global__ void smooth_fwd(const float* __restrict__ in, float* __restrict__ out,
                           const float* __restrict__ gwb, int n, int stride) {
    int e = blockIdx.x * 256 + threadIdx.x;
    if (e >= NVOX) return;
    int a = (e / stride) % n;
    int base = e - a * stride;
    float sum = 0.f;
#pragma unroll
    for (int k = 0; k < 9; ++k) {
        int q = a + k - 4;
        q = (q < 0) ? (-1 - q) : ((q >= n) ? (2 * n - 1 - q) : q);
        sum = __fadd_rn(sum, __fmul_rn(gwb[k], in[base + q * stride]));
    }
    out[e] = sum;
}

// axis-2 pass that also writes the per-slice transposed copy outT[i0][i2][i1]
__global__ void smooth_fwd2_dual(const float* __restrict__ in, float* __restrict__ out,
                                 float* __restrict__ outT, const float* __restrict__ gwb) {
    int e = blockIdx.x * 256 + threadIdx.x;
    if (e >= NVOX) return;
    int a = e % N2;                 // i2
    int base = e - a;
    float sum = 0.f;
#pragma unroll
    for (int k = 0; k < 9; ++k) {
        int q = a + k - 4;
        q = (q < 0) ? (-1 - q) : ((q >= N2) ? (2 * N2 - 1 - q) : q);
        sum = __fadd_rn(sum, __fmul_rn(gwb[k], in[base + q]));
    }
    out[e] = sum;
    int i0 = e / NPIX;
    int rem = e - i0 * NPIX;
    int i1 = rem / N2;              // row
    outT[i0 * NPIX + a * N1 + i1] = sum;
}

// ---------------- separable gaussian, adjoint (pad-transpose fold) ----------------
__device__ __forceinline__ float adj_u(const float* __restrict__ in, const float* __restrict__ gwb,
                                       int base, int stride, int n, int j) {
    float r = 0.f;
#pragma unroll
    for (int k = 0; k < 9; ++k) {
        int i = j - k;
        if (i >= 0 && i < n) r = __fadd_rn(r, __fmul_rn(gwb[k], in[base + i * stride]));
    }
    return r;
}

__global__ void smooth_adj(const float* __restrict__ in, float* __restrict__ out,
                           const float* __restrict__ gwb, int n, int stride) {
    int e = blockIdx.x * 256 + threadIdx.x;
    if (e >= NVOX) return;
    int a = (e / stride) % n;
    int base = e - a * stride;
    float v = adj_u(in, gwb, base, stride, n, a + 4);
    if (a < 4)      v = __fadd_rn(v, adj_u(in, gwb, base, stride, n, 3 - a));
    if (a >= n - 4) v = __fadd_rn(v, adj_u(in, gwb, base, stride, n, 2 * n + 3 - a));
    out[e] = v;
}

// final axis-0 adjoint pass fused with  out = x * v / sens
__global__ void smooth_adj0_final(const float* __restrict__ in, const float* __restrict__ x,
                                  const float* __restrict__ sens, const float* __restrict__ gwb,
                                  float* __restrict__ out) {
    int e = blockIdx.x * 256 + threadIdx.x;
    if (e >= NVOX) return;
    int a = e / NPIX;
    int base = e - a * NPIX;
    float v = adj_u(in, gwb, base, NPIX, N0, a + 4);
    if (a < 4)  v = __fadd_rn(v, adj_u(in, gwb, base, NPIX, N0, 3 - a));
    if (a >= 12) v = __fadd_rn(v, adj_u(in, gwb, base, NPIX, N0, 35 - a));
    out[e] = __fdiv_rn(__fmul_rn(x[e], v), sens[e]);
}

// ---------------- forward projection + ratio, fused ----------------
// block: (phi, i0-pair), thread = radial bin r; each thread traces one ray
// through TWO slices. Per-phi layout selection (normal vs transposed slice)
// keeps r-adjacent threads contiguous in memory for every angle.
__global__ void project_ratio(const float* __restrict__ simg, const float* __restrict__ simgT,
                              const float* __restrict__ data,
                              const float* __restrict__ contam, const float* __restrict__ mult,
                              const float* __restrict__ cosb, const float* __restrict__ sinb,
                              const float* __restrict__ rvb, float* __restrict__ zt) {
    int phi = blockIdx.x;
    int i0 = blockIdx.y * 2;
    int r = threadIdx.x;
    if (r >= NUM_RAD) return;
    float c = cosb[phi], sp = sinb[phi];
    float rv = rvb[r];
    float A = __fmul_rn(rv, -sp);   // RV * (-s)
    float B = __fmul_rn(rv, c);     // RV * c

    // layout select: make the r-varying pixel direction contiguous
    bool useT = fabsf(sp) > fabsf(c);
    int sI = useT ? 1 : N2;
    int sJ = useT ? N1 : 1;
    const float* sl0 = (useT ? simgT : simg) + i0 * NPIX;
    const float* sl1 = sl0 + NPIX;

    // conservative valid-t window: A + tv*c in [-199,199] and B + tv*sp in [-199,199]
    float tlo = -350.f, thi = 350.f;
    bool empty = false;
    {
        if (fabsf(c) > 1e-6f) {
            float a0 = (-199.f - A) / c, b0 = (199.f - A) / c;
            tlo = fmaxf(tlo, fminf(a0, b0)); thi = fminf(thi, fmaxf(a0, b0));
        } else if (fabsf(A) > 199.5f) empty = true;
        if (fabsf(sp) > 1e-6f) {
            float a0 = (-199.f - B) / sp, b0 = (199.f - B) / sp;
            tlo = fmaxf(tlo, fminf(a0, b0)); thi = fminf(thi, fmaxf(a0, b0));
        } else if (fabsf(B) > 199.5f) empty = true;
    }
    int klo = max(0, (int)floorf((tlo + 350.f) * 0.5f) - 1);
    int khi = min(NUM_T - 1, (int)ceilf((thi + 350.f) * 0.5f) + 1);

    float sum0 = 0.f, sum1 = 0.f;
    if (!empty && klo <= khi) {
#pragma unroll 4
        for (int k = klo; k <= khi; ++k) {
            float tv = (float)(2 * k - 350);
            float ix = __fmul_rn(__fsub_rn(__fadd_rn(A, __fmul_rn(tv, c)), ORG1F), 0.5f);
            float iy = __fmul_rn(__fsub_rn(__fadd_rn(B, __fmul_rn(tv, sp)), ORG2F), 0.5f);
            bool valid = (ix >= 0.f && ix <= 199.f && iy >= 0.f && iy <= 199.f);
            float fx = floorf(ix), fy = floorf(iy);
            int ii = (int)fx, jj = (int)fy;
            float fi = ix - fx, fj = iy - fy;
            int ii0 = min(max(ii, 0), 199), jj0 = min(max(jj, 0), 199);
            int ii1 = min(ii0 + 1, 199),   jj1 = min(jj0 + 1, 199);
            float w00 = (1.f - fi) * (1.f - fj), w10 = fi * (1.f - fj);
            float w01 = (1.f - fi) * fj,         w11 = fi * fj;
            int o00 = ii0 * sI + jj0 * sJ, o10 = ii1 * sI + jj0 * sJ;
            int o01 = ii0 * sI + jj1 * sJ, o11 = ii1 * sI + jj1 * sJ;
            float v0 = w00 * sl0[o00] + w10 * sl0[o10] + w01 * sl0[o01] + w11 * sl0[o11];
            float v1 = w00 * sl1[o00] + w10 * sl1[o10] + w01 * sl1[o01] + w11 * sl1[o11];
            float m = valid ? 1.f : 0.f;
            sum0 = __fadd_rn(sum0, __fmul_rn(v0, m));
            sum1 = __fadd_rn(sum1, __fmul_rn(v1, m));
        }
    }
#pragma unroll
    for (int s = 0; s < 2; ++s) {
        float proj = __fmul_rn(s ? sum1 : sum0, 2.0f);  // * STEP
        int sl = i0 + s;
        int idx = (sl * NUM_PHI + phi) * NUM_RAD + r;
        float ex = __fadd_rn(__fmul_rn(mult[idx], proj), contam[idx]);
        float zval = __fmul_rn(mult[idx], __fdiv_rn(data[idx], ex));
        zt[(phi * NUM_RAD + r) * N0 + sl] = zval;
    }
}

// ---------------- adjoint projection, gather form ----------------
// thread = (pixel, phi-chunk of 19). Accumulates all 16 slices, atomicAdd into bp[i0][pix].
__global__ void backproject(const float* __restrict__ zt, const float* __restrict__ cosb,
                            const float* __restrict__ sinb, const float* __restrict__ rvb,
                            float* __restrict__ bp) {
    int g = blockIdx.x * 256 + threadIdx.x;
    if (g >= NPIX * 10) return;
    int pc = g / NPIX;
    int pix = g - pc * NPIX;
    int i1 = pix / N2;
    int i2 = pix - i1 * N2;
    float X1 = 2.f * (float)i1 - 199.f;   // ORG1 + i1*VOX (exact)
    float X2 = 2.f * (float)i2 - 199.f;
    float acc[N0];
#pragma unroll
    for (int i0 = 0; i0 < N0; ++i0) acc[i0] = 0.f;

    int p_end = pc * 19 + 19;
    for (int p = pc * 19; p < p_end; ++p) {
        float c = cosb[p], sp = sinb[p];
        float tp = c * X1 + sp * X2;      // candidate location only (precision uncritical)
        float rp = c * X2 - sp * X1;
        int j0 = (int)floorf((rp + 200.f) * 0.555f);   // 222/400
        int k0 = (int)floorf((tp + 350.f) * 0.5f);
        for (int dj = -1; dj <= 2; ++dj) {
            int j = j0 + dj;
            if (j < 0 || j > NUM_RAD - 1) continue;
            float rv = rvb[j];
            float A = __fmul_rn(rv, -sp);
            float B = __fmul_rn(rv, c);
            float w = 0.f;
            for (int dk = -1; dk <= 2; ++dk) {
                int k = k0 + dk;
                if (k < 0 || k > NUM_T - 1) continue;
                float tv = (float)(2 * k - 350);
                // EXACT same op sequence as forward -> identical ix/iy/validity
                float ix = __fmul_rn(__fsub_rn(__fadd_rn(A, __fmul_rn(tv, c)), ORG1F), 0.5f);
                float iy = __fmul_rn(__fsub_rn(__fadd_rn(B, __fmul_rn(tv, sp)), ORG2F), 0.5f);
                if (!(ix >= 0.f && ix <= 199.f && iy >= 0.f && iy <= 199.f)) continue;
                float fx = floorf(ix), fy = floorf(iy);
                int ii = (int)fx, jj = (int)fy;
                float fi = ix - fx, fj = iy - fy;
                float wx = (ii == i1) ? (1.f - fi) : ((ii + 1 == i1) ? fi : 0.f);
                if (wx == 0.f) continue;
                float wy = (jj == i2) ? (1.f - fj) : ((jj + 1 == i2) ? fj : 0.f);
                w += wx * wy;
            }
            if (w != 0.f) {
                const float* zp = zt + (p * NUM_RAD + j) * N0;
#pragma unroll
                for (int i0 = 0; i0 < N0; ++i0) acc[i0] += w * zp[i0];
            }
        }
    }
#pragma unroll
    for (int i0 = 0; i0 < N0; ++i0)
        atomicAdd(&bp[i0 * NPIX + pix], acc[i0] * 2.0f);  // * STEP
}

extern "C" void kernel_launch(void* const* d_in, const int* in_sizes, int n_in,
                              void* d_out, int out_size, void* d_ws, size_t ws_size,
                              hipStream_t stream) {
    const float* x      = (const float*)d_in[0];
    const float* data   = (const float*)d_in[1];
    const float* contam = (const float*)d_in[2];
    const float* mult   = (const float*)d_in[3];
    const float* sens   = (const float*)d_in[4];
    float* out = (float*)d_out;

    float* W    = (float*)d_ws;
    float* s    = W;                       // 640000
    float* tmp  = W + NVOX;                // 640000
    float* bp   = W + 2 * NVOX;            // 640000
    float* sT   = W + 3 * NVOX;            // 640000 (transposed smoothed image)
    float* zt   = W + 4 * NVOX;            // 677920
    float* cosb = W + 4 * NVOX + NSINO;
    float* sinb = cosb + NUM_PHI;
    float* rvb  = sinb + NUM_PHI;
    float* gwb  = rvb + NUM_RAD;

    hipLaunchKernelGGL(init_consts, dim3(1), dim3(256), 0, stream, cosb, sinb, rvb, gwb);

    // gauss3 forward: x -> s (axis0), s -> tmp (axis1), tmp -> {s, sT} (axis2 dual-store)
    int nb = (NVOX + 255) / 256;
    hipLaunchKernelGGL(smooth_fwd, dim3(nb), dim3(256), 0, stream, x,   s,   gwb, N0, NPIX);
    hipLaunchKernelGGL(smooth_fwd, dim3(nb), dim3(256), 0, stream, s,   tmp, gwb, N1, N2);
    hipLaunchKernelGGL(smooth_fwd2_dual, dim3(nb), dim3(256), 0, stream, tmp, s, sT, gwb);

    // forward project + ratio (writes zt), 2 slices per thread
    hipLaunchKernelGGL(project_ratio, dim3(NUM_PHI, N0 / 2), dim3(256), 0, stream,
                       s, sT, data, contam, mult, cosb, sinb, rvb, zt);

    // backproject (gather) into bp
    hipMemsetAsync(bp, 0, NVOX * sizeof(float), stream);
    int nb2 = (NPIX * 10 + 255) / 256;
    hipLaunchKernelGGL(backproject, dim3(nb2), dim3(256), 0, stream, zt, cosb, sinb, rvb, bp);

    // gauss3 adjoint: bp -> tmp (axis2^T), tmp -> bp (axis1^T), bp -> out (axis0^T fused final)
    hipLaunchKernelGGL(smooth_adj, dim3(nb), dim3(256), 0, stream, bp,  tmp, gwb, N2, 1);
    hipLaunchKernelGGL(smooth_adj, dim3(nb), dim3(256), 0, stream, tmp, bp,  gwb, N1, N2);
    hipLaunchKernelGGL(smooth_adj0_final, dim3(nb), dim3(256), 0, stream, bp, x, sens, gwb, out);
}